// Round 1
// baseline (330.598 us; speedup 1.0000x reference)
//
#include <hip/hip_runtime.h>

// Workspace-free MoE output combine.
//
// Direction of iteration is over expert slots (scatter), not tokens (gather):
//   rows j in [0, n):       t = scatter_idx[j]; if t < T: out[t] = eo[j] * rpm[t]
//   rows n + t, t in [0,T): if dropped_mask[t]: out[t] = x[t]
// By construction every token is exactly one of {kept-in-scatter, dropped},
// so out is fully written. Kept slots have unique t -> no write conflicts.
// This removes the inverse-map scratch table entirely (no d_ws use, no
// hipMemsetAsync, no build pass): the harness's 640 MiB workspace re-poison
// fill (~100 us/iter at 84% HBM peak, the dominant timed dispatch) should
// drop out of the timed window.
__global__ void moe_combine_kernel(const float4* __restrict__ eo,
                                   const float4* __restrict__ x,
                                   const float* __restrict__ rpm,
                                   const int* __restrict__ scatter_idx,
                                   const unsigned char* __restrict__ dropped,
                                   float4* __restrict__ out,
                                   int n, int T, int D4) {
    int row = blockIdx.y;
    int c = blockIdx.x * blockDim.x + threadIdx.x;   // 0..D4-1 (D4 % 256 == 0)

    if (row < n) {
        // Scatter path: copy expert output row to its token, scaled by rpm.
        int t = scatter_idx[row];                     // block-uniform
        if ((unsigned)t >= (unsigned)T) return;       // padding slot
        float f = rpm[t];
        float4 v = eo[(size_t)row * D4 + c];          // contiguous 8 KB row
        v.x *= f; v.y *= f; v.z *= f; v.w *= f;
        out[(size_t)t * D4 + c] = v;                  // contiguous 8 KB row
    } else {
        // Dropped path: pass-through x with factor 1.0. Expected ~0 tokens
        // dropped (C = 1.25*T/E), so these blocks early-exit on a 1-byte read.
        int t = row - n;
        if (!dropped[t]) return;                      // block-uniform
        out[(size_t)t * D4 + c] = x[(size_t)t * D4 + c];
    }
}

extern "C" void kernel_launch(void* const* d_in, const int* in_sizes, int n_in,
                              void* d_out, int out_size, void* d_ws, size_t ws_size,
                              hipStream_t stream) {
    const float* eo            = (const float*)d_in[0];          // (E*C, D) fp32
    const float* x             = (const float*)d_in[1];          // (B, S, D) fp32
    const float* rpm           = (const float*)d_in[2];          // (T,) fp32
    const int*   scatter_idx   = (const int*)d_in[3];            // (E*C,) int32
    const unsigned char* dmask = (const unsigned char*)d_in[4];  // (T,) bool

    const int T  = in_sizes[2];        // 16384 tokens
    const int D  = in_sizes[1] / T;    // 2048
    const int n  = in_sizes[3];        // E*C = 20480 slots
    const int D4 = D / 4;              // 512 float4 per row

    // grid.x = 2 blocks x 256 threads covers one D4=512 row exactly.
    dim3 grid((D4 + 255) / 256, n + T);
    moe_combine_kernel<<<grid, 256, 0, stream>>>(
        (const float4*)eo, (const float4*)x, rpm, scatter_idx, dmask,
        (float4*)d_out, n, T, D4);
}

// Round 3
// 325.663 us; speedup vs baseline: 1.0152x; 1.0152x over previous
//
#include <hip/hip_runtime.h>

// MoE output combine, workspace-free, dispatch-lean.
// (Round-2 design resubmitted after an infra-level bench failure; logic
// unchanged, unroll-with-break replaced by a plain guard.)
//
// Work decomposition (single kernel, 256 threads/block):
//   blocks [0, nRowBlocks):  scatter path. Each block copies ROWS_PER_BLOCK=4
//       expert rows: t = scatter_idx[j]; if t < T: out[t] = eo[j] * rpm[t].
//       Rows are 8 KB contiguous both sides; 2 float4 per thread per row.
//   blocks [nRowBlocks, +T/256): dropped path. Each block scans 256 mask
//       bytes into an LDS list, then cooperatively copies x->out for each
//       dropped token. Expected dropped count ~0 (C = 1.25*T/E), so this is
//       a 16 KiB scan, not 32k near-empty blocks.
// Every token is either kept (in scatter_idx) or dropped, so out is fully
// written; kept slots map to unique t -> no write conflicts.
//
// NOTE (round-1 post-mortem): the ~100 us 640 MiB fillBufferAligned in the
// timed window is the harness's unconditional workspace poison - it persists
// with zero d_ws use and cannot be optimized from here. Only the combine
// kernel's share of the window is addressable.

#define ROWS_PER_BLOCK 4

__global__ void moe_combine_kernel(const float4* __restrict__ eo,
                                   const float4* __restrict__ x,
                                   const float* __restrict__ rpm,
                                   const int* __restrict__ sidx,
                                   const unsigned char* __restrict__ dmask,
                                   float4* __restrict__ out,
                                   int nRowBlocks, int n, int T, int D4) {
    if ((int)blockIdx.x < nRowBlocks) {
        // ---- scatter path: 4 expert rows per block ----
        int j0 = blockIdx.x * ROWS_PER_BLOCK;
        #pragma unroll
        for (int r = 0; r < ROWS_PER_BLOCK; ++r) {
            int j = j0 + r;
            if (j < n) {
                int t = sidx[j];                           // block-uniform
                if ((unsigned)t < (unsigned)T) {           // skip padding slots
                    float f = rpm[t];
                    const float4* __restrict__ src = eo + (size_t)j * D4;
                    float4*       __restrict__ dst = out + (size_t)t * D4;
                    for (int c = threadIdx.x; c < D4; c += blockDim.x) {
                        float4 v = src[c];
                        v.x *= f; v.y *= f; v.z *= f; v.w *= f;
                        dst[c] = v;
                    }
                }
            }
        }
    } else {
        // ---- dropped path: scan 256 tokens' masks, copy any dropped rows ----
        int base = (blockIdx.x - nRowBlocks) * blockDim.x;
        __shared__ int list[256];
        __shared__ int cnt;
        if (threadIdx.x == 0) cnt = 0;
        __syncthreads();
        int t = base + threadIdx.x;
        if (t < T && dmask[t]) {
            int i = atomicAdd(&cnt, 1);
            if (i < 256) list[i] = t;
        }
        __syncthreads();
        int m = cnt < 256 ? cnt : 256;
        for (int i = 0; i < m; ++i) {
            int td = list[i];
            const float4* __restrict__ src = x + (size_t)td * D4;
            float4*       __restrict__ dst = out + (size_t)td * D4;
            for (int c = threadIdx.x; c < D4; c += blockDim.x)
                dst[c] = src[c];
        }
    }
}

extern "C" void kernel_launch(void* const* d_in, const int* in_sizes, int n_in,
                              void* d_out, int out_size, void* d_ws, size_t ws_size,
                              hipStream_t stream) {
    const float* eo            = (const float*)d_in[0];          // (E*C, D) fp32
    const float* x             = (const float*)d_in[1];          // (B, S, D) fp32
    const float* rpm           = (const float*)d_in[2];          // (T,) fp32
    const int*   scatter_idx   = (const int*)d_in[3];            // (E*C,) int32
    const unsigned char* dmask = (const unsigned char*)d_in[4];  // (T,) bool

    const int T  = in_sizes[2];        // 16384 tokens
    const int D  = in_sizes[1] / T;    // 2048
    const int n  = in_sizes[3];        // E*C = 20480 slots
    const int D4 = D / 4;              // 512 float4 per row

    const int nRowBlocks  = (n + ROWS_PER_BLOCK - 1) / ROWS_PER_BLOCK;  // 5120
    const int nMaskBlocks = (T + 255) / 256;                            // 64

    moe_combine_kernel<<<nRowBlocks + nMaskBlocks, 256, 0, stream>>>(
        (const float4*)eo, (const float4*)x, rpm, scatter_idx, dmask,
        (float4*)d_out, nRowBlocks, n, T, D4);
}